// Round 2
// baseline (367.470 us; speedup 1.0000x reference)
//
#include <hip/hip_runtime.h>
#include <math.h>

#define NCLS 21
#define NGT 32
#define CLIPLEN 256.0f
#define MAXN 512.0f
#define FEPS 1.1920928955078125e-07f

#define ROWF 21            // floats per class row
#define WCH (64 * ROWF)    // floats per wave chunk (64 anchors) = 1344

// acc layout (doubles): 0 loss_l, 1 loss_c, 2 loss_prop_l, 3 loss_prop_c,
//                       4 loss_ct, 5 pos_count, 6 prop_pos_count

__device__ __forceinline__ void glds16(const float* g, float* l) {
    __builtin_amdgcn_global_load_lds(
        (const __attribute__((address_space(1))) void*)g,
        (__attribute__((address_space(3))) void*)l, 16, 0, 0);
}
__device__ __forceinline__ void glds4(const float* g, float* l) {
    __builtin_amdgcn_global_load_lds(
        (const __attribute__((address_space(1))) void*)g,
        (__attribute__((address_space(3))) void*)l, 4, 0, 0);
}

__device__ __forceinline__ float focal_term_lds(const float* __restrict__ row, int tgt) {
    float r[NCLS];
#pragma unroll
    for (int i = 0; i < NCLS; ++i) r[i] = row[i];   // ds_read, conflict-free
    float m = r[0];
#pragma unroll
    for (int i = 1; i < NCLS; ++i) m = fmaxf(m, r[i]);
    float s = 0.0f;
    float tl = 0.0f;
#pragma unroll
    for (int i = 0; i < NCLS; ++i) {
        s += __expf(r[i] - m);
        if (i == tgt) tl = r[i];      // compile-time index, runtime select
    }
    float lse = m + __logf(s);
    float pt = __expf(tl - lse) + 1e-10f;
    float a = (tgt == 0) ? 0.25f : 0.75f;
    float om = 1.0f - pt;
    return -a * om * om * __logf(pt);
}

__global__ __launch_bounds__(256) void msl_main(
    const float* __restrict__ loc_data,
    const float* __restrict__ conf_data,
    const float* __restrict__ prop_loc_data,
    const float* __restrict__ prop_conf_data,
    const float* __restrict__ center_data,
    const float* __restrict__ priors,
    const float* __restrict__ targets,
    double* __restrict__ acc,
    int K)
{
    __shared__ float s_cls[2][4 * WCH];   // [conf | prop_conf] x 4 waves, 43008 B
    __shared__ float s_t0[NGT], s_t1[NGT], s_lb[NGT];
    __shared__ float s_red[7 * 4];

    const int b    = blockIdx.y;
    const int tid  = threadIdx.x;
    const int lane = tid & 63;
    const int w    = tid >> 6;
    const int kblk = blockIdx.x * 256;
    const int k    = kblk + tid;
    const size_t idx = (size_t)b * K + k;

    if (tid < NGT) {
        const float* tg = targets + ((size_t)b * NGT + tid) * 3;
        s_t0[tid] = tg[0];
        s_t1[tid] = tg[1];
        s_lb[tid] = tg[2];
    }

    // ---- async global->LDS staging of this wave's 64 class rows ----
    {
        const size_t chunk0 = ((size_t)b * K + kblk + w * 64) * ROWF;
        const float* gc = conf_data + chunk0;
        const float* gp = prop_conf_data + chunk0;
        float* lc = &s_cls[0][w * WCH];
        float* lp = &s_cls[1][w * WCH];
#pragma unroll
        for (int i = 0; i < 5; ++i)                 // 5 x 1024B (dwordx4)
            glds16(gc + i * 256 + lane * 4, lc + i * 256);
        glds4(gc + 1280 + lane, lc + 1280);         // tail 256B (dword)
#pragma unroll
        for (int i = 0; i < 5; ++i)
            glds16(gp + i * 256 + lane * 4, lp + i * 256);
        glds4(gp + 1280 + lane, lp + 1280);
    }

    // ---- per-anchor small loads (coalesced) ----
    const float2 loc = ((const float2*)loc_data)[idx];
    const float2 plo = ((const float2*)prop_loc_data)[idx];
    const float  x   = center_data[idx];
    const float  c   = priors[k];

    __syncthreads();   // targets visible; also drains vmcnt (glds done)

    // ---- match: argmin over 32 GTs (first occurrence of min) ----
    float bestA = 3.0e38f;
    int bestN = 0;
#pragma unroll
    for (int n = 0; n < NGT; ++n) {
        float l = (c - s_t0[n]) * CLIPLEN;
        float r = (s_t1[n] - c) * CLIPLEN;
        float a = (l < 0.0f || r < 0.0f) ? MAXN : (l + r);
        if (a < bestA) { bestA = a; bestN = n; }
    }
    const float t0 = s_t0[bestN];
    const float t1 = s_t1[bestN];
    const float tl = (c - t0) * CLIPLEN;
    const float tr = (t1 - c) * CLIPLEN;
    int conf_t = (bestA >= MAXN) ? 0 : (int)s_lb[bestN];

    const float pl = loc.x, pr = loc.y;

    // ---- IoU(loc_data, loc_t) ----
    const float inter = fminf(pl, tl) + fminf(pr, tr);
    const float uni   = pl + pr + tl + tr - inter;
    const float iou   = inter / fmaxf(uni, FEPS);

    const int prop_conf_t = (iou < 0.5f) ? 0 : conf_t;
    const float posf = (conf_t > 0) ? 1.0f : 0.0f;
    const float ppf  = (prop_conf_t > 0) ? 1.0f : 0.0f;

    // ---- loss_l: GIoU ----
    const float ac   = fmaxf(pl, tl) + fmaxf(pr, tr);
    const float giou = iou - (ac - uni) / fmaxf(ac, FEPS);
    const float v_ll = (1.0f - giou) * posf;

    // ---- loss_prop_l ----
    const float prop_w = pl + pr;
    const float inv_hw = 1.0f / (0.5f * prop_w);
    const float plt0 = (tl - pl) * inv_hw;
    const float plt1 = (tr - pr) * inv_hw;
    const float v_lpl = (fabsf(plo.x - plt0) + fabsf(plo.y - plt1)) * ppf;

    // ---- loss_ct ----
    const float cur0 = 0.5f * prop_w * plo.x + pl;
    const float cur1 = 0.5f * prop_w * plo.y + pr;
    const float in2  = fminf(cur0, tl) + fminf(cur1, tr);
    const float un2  = cur0 + cur1 + tl + tr - in2;
    const float iou2 = fmaxf(in2 / fmaxf(un2, FEPS), 0.0f);
    const float bce  = fmaxf(x, 0.0f) - x * iou2 + log1pf(__expf(-fabsf(x)));
    const float v_ct = bce * posf;

    // ---- focal terms from LDS ----
    asm volatile("s_waitcnt vmcnt(0)" ::: "memory");
    const float* rowc = &s_cls[0][w * WCH + lane * ROWF];
    const float* rowp = &s_cls[1][w * WCH + lane * ROWF];
    const float v_lc  = focal_term_lds(rowc, conf_t);
    const float v_lpc = focal_term_lds(rowp, prop_conf_t);

    // ---- block reduction ----
    float vals[7] = { v_ll, v_lc, v_lpl, v_lpc, v_ct, posf, ppf };
#pragma unroll
    for (int i = 0; i < 7; ++i) {
        float v = vals[i];
#pragma unroll
        for (int off = 32; off > 0; off >>= 1) v += __shfl_xor(v, off);
        if (lane == 0) s_red[i * 4 + w] = v;
    }
    __syncthreads();
    if (tid == 0) {
#pragma unroll
        for (int i = 0; i < 7; ++i) {
            double s = (double)s_red[i * 4 + 0] + (double)s_red[i * 4 + 1]
                     + (double)s_red[i * 4 + 2] + (double)s_red[i * 4 + 3];
            atomicAdd(&acc[i], s);
        }
    }
}

__global__ void msl_finalize(const double* __restrict__ acc, float* __restrict__ out) {
    const double N  = fmax(acc[5], 1.0);
    const double PN = fmax(acc[6], 1.0);
    out[0] = (float)(acc[0] / N);   // loss_l
    out[1] = (float)(acc[1] / N);   // loss_c
    out[2] = (float)(acc[2] / PN);  // loss_prop_l
    out[3] = (float)(acc[3] / PN);  // loss_prop_c
    out[4] = (float)(acc[4] / N);   // loss_ct
}

extern "C" void kernel_launch(void* const* d_in, const int* in_sizes, int n_in,
                              void* d_out, int out_size, void* d_ws, size_t ws_size,
                              hipStream_t stream) {
    const float* loc_data       = (const float*)d_in[0];
    const float* conf_data      = (const float*)d_in[1];
    const float* prop_loc_data  = (const float*)d_in[2];
    const float* prop_conf_data = (const float*)d_in[3];
    const float* center_data    = (const float*)d_in[4];
    const float* priors         = (const float*)d_in[5];
    const float* targets        = (const float*)d_in[6];
    float* out = (float*)d_out;

    const int K = in_sizes[5];            // priors: (K, 1)
    const int B = in_sizes[6] / (NGT * 3);

    double* acc = (double*)d_ws;
    hipMemsetAsync(acc, 0, 7 * sizeof(double), stream);

    dim3 grid(K / 256, B);
    msl_main<<<grid, 256, 0, stream>>>(loc_data, conf_data, prop_loc_data,
                                       prop_conf_data, center_data, priors,
                                       targets, acc, K);
    msl_finalize<<<1, 1, 0, stream>>>(acc, out);
}

// Round 3
// 77.362 us; speedup vs baseline: 4.7500x; 4.7500x over previous
//
#include <hip/hip_runtime.h>
#include <math.h>

#define NCLS 21
#define NGT 32
#define CLIPLEN 256.0f
#define MAXN 512.0f
#define FEPS 1.1920928955078125e-07f

#define ROWF 21            // floats per class row
#define WCH (64 * ROWF)    // floats per wave chunk (64 anchors) = 1344

// partial layout in d_ws (doubles): p[i * nblk + blk], i in 0..6
// i: 0 loss_l, 1 loss_c, 2 loss_prop_l, 3 loss_prop_c, 4 loss_ct, 5 pos, 6 prop_pos

__device__ __forceinline__ void glds16(const float* g, float* l) {
    __builtin_amdgcn_global_load_lds(
        (const __attribute__((address_space(1))) void*)g,
        (__attribute__((address_space(3))) void*)l, 16, 0, 0);
}
__device__ __forceinline__ void glds4(const float* g, float* l) {
    __builtin_amdgcn_global_load_lds(
        (const __attribute__((address_space(1))) void*)g,
        (__attribute__((address_space(3))) void*)l, 4, 0, 0);
}

__device__ __forceinline__ float focal_term_lds(const float* __restrict__ row, int tgt) {
    float r[NCLS];
#pragma unroll
    for (int i = 0; i < NCLS; ++i) r[i] = row[i];   // ds_read, conflict-free
    float m = r[0];
#pragma unroll
    for (int i = 1; i < NCLS; ++i) m = fmaxf(m, r[i]);
    float s = 0.0f;
    float tl = 0.0f;
#pragma unroll
    for (int i = 0; i < NCLS; ++i) {
        s += __expf(r[i] - m);
        if (i == tgt) tl = r[i];      // compile-time index, runtime select
    }
    float lse = m + __logf(s);
    float pt = __expf(tl - lse) + 1e-10f;
    float a = (tgt == 0) ? 0.25f : 0.75f;
    float om = 1.0f - pt;
    return -a * om * om * __logf(pt);
}

template <bool PARTIALS>
__global__ __launch_bounds__(256) void msl_main(
    const float* __restrict__ loc_data,
    const float* __restrict__ conf_data,
    const float* __restrict__ prop_loc_data,
    const float* __restrict__ prop_conf_data,
    const float* __restrict__ center_data,
    const float* __restrict__ priors,
    const float* __restrict__ targets,
    double* __restrict__ ws,
    int K, int nblk)
{
    __shared__ float s_cls[2][4 * WCH];   // [conf | prop_conf] x 4 waves, 43008 B
    __shared__ float s_t0[NGT], s_t1[NGT], s_lb[NGT];
    __shared__ float s_red[7 * 4];

    const int b    = blockIdx.y;
    const int tid  = threadIdx.x;
    const int lane = tid & 63;
    const int w    = tid >> 6;
    const int kblk = blockIdx.x * 256;
    const int k    = kblk + tid;
    const size_t idx = (size_t)b * K + k;

    if (tid < NGT) {
        const float* tg = targets + ((size_t)b * NGT + tid) * 3;
        s_t0[tid] = tg[0];
        s_t1[tid] = tg[1];
        s_lb[tid] = tg[2];
    }

    // ---- async global->LDS staging of this wave's 64 class rows ----
    {
        const size_t chunk0 = ((size_t)b * K + kblk + w * 64) * ROWF;
        const float* gc = conf_data + chunk0;
        const float* gp = prop_conf_data + chunk0;
        float* lc = &s_cls[0][w * WCH];
        float* lp = &s_cls[1][w * WCH];
#pragma unroll
        for (int i = 0; i < 5; ++i)                 // 5 x 1024B (dwordx4)
            glds16(gc + i * 256 + lane * 4, lc + i * 256);
        glds4(gc + 1280 + lane, lc + 1280);         // tail 256B (dword)
#pragma unroll
        for (int i = 0; i < 5; ++i)
            glds16(gp + i * 256 + lane * 4, lp + i * 256);
        glds4(gp + 1280 + lane, lp + 1280);
    }

    // ---- per-anchor small loads (coalesced) ----
    const float2 loc = ((const float2*)loc_data)[idx];
    const float2 plo = ((const float2*)prop_loc_data)[idx];
    const float  x   = center_data[idx];
    const float  c   = priors[k];

    __syncthreads();   // targets visible

    // ---- match: argmin over 32 GTs (first occurrence of min) ----
    float bestA = 3.0e38f;
    int bestN = 0;
#pragma unroll
    for (int n = 0; n < NGT; ++n) {
        float l = (c - s_t0[n]) * CLIPLEN;
        float r = (s_t1[n] - c) * CLIPLEN;
        float a = (l < 0.0f || r < 0.0f) ? MAXN : (l + r);
        if (a < bestA) { bestA = a; bestN = n; }
    }
    const float t0 = s_t0[bestN];
    const float t1 = s_t1[bestN];
    const float tl = (c - t0) * CLIPLEN;
    const float tr = (t1 - c) * CLIPLEN;
    int conf_t = (bestA >= MAXN) ? 0 : (int)s_lb[bestN];

    const float pl = loc.x, pr = loc.y;

    // ---- IoU(loc_data, loc_t) ----
    const float inter = fminf(pl, tl) + fminf(pr, tr);
    const float uni   = pl + pr + tl + tr - inter;
    const float iou   = inter / fmaxf(uni, FEPS);

    const int prop_conf_t = (iou < 0.5f) ? 0 : conf_t;
    const float posf = (conf_t > 0) ? 1.0f : 0.0f;
    const float ppf  = (prop_conf_t > 0) ? 1.0f : 0.0f;

    // ---- loss_l: GIoU ----
    const float ac   = fmaxf(pl, tl) + fmaxf(pr, tr);
    const float giou = iou - (ac - uni) / fmaxf(ac, FEPS);
    const float v_ll = (1.0f - giou) * posf;

    // ---- loss_prop_l ----
    const float prop_w = pl + pr;
    const float inv_hw = 1.0f / (0.5f * prop_w);
    const float plt0 = (tl - pl) * inv_hw;
    const float plt1 = (tr - pr) * inv_hw;
    const float v_lpl = (fabsf(plo.x - plt0) + fabsf(plo.y - plt1)) * ppf;

    // ---- loss_ct ----
    const float cur0 = 0.5f * prop_w * plo.x + pl;
    const float cur1 = 0.5f * prop_w * plo.y + pr;
    const float in2  = fminf(cur0, tl) + fminf(cur1, tr);
    const float un2  = cur0 + cur1 + tl + tr - in2;
    const float iou2 = fmaxf(in2 / fmaxf(un2, FEPS), 0.0f);
    const float bce  = fmaxf(x, 0.0f) - x * iou2 + log1pf(__expf(-fabsf(x)));
    const float v_ct = bce * posf;

    // ---- focal terms from LDS ----
    asm volatile("s_waitcnt vmcnt(0)" ::: "memory");
    const float* rowc = &s_cls[0][w * WCH + lane * ROWF];
    const float* rowp = &s_cls[1][w * WCH + lane * ROWF];
    const float v_lc  = focal_term_lds(rowc, conf_t);
    const float v_lpc = focal_term_lds(rowp, prop_conf_t);

    // ---- block reduction ----
    float vals[7] = { v_ll, v_lc, v_lpl, v_lpc, v_ct, posf, ppf };
#pragma unroll
    for (int i = 0; i < 7; ++i) {
        float v = vals[i];
#pragma unroll
        for (int off = 32; off > 0; off >>= 1) v += __shfl_xor(v, off);
        if (lane == 0) s_red[i * 4 + w] = v;
    }
    __syncthreads();
    if (tid == 0) {
        const int blk = blockIdx.y * gridDim.x + blockIdx.x;
#pragma unroll
        for (int i = 0; i < 7; ++i) {
            double s = (double)s_red[i * 4 + 0] + (double)s_red[i * 4 + 1]
                     + (double)s_red[i * 4 + 2] + (double)s_red[i * 4 + 3];
            if (PARTIALS) ws[(size_t)i * nblk + blk] = s;   // contention-free store
            else          atomicAdd(&ws[i], s);
        }
    }
}

// Single-block deterministic reduction of per-block partials -> 5 outputs.
__global__ __launch_bounds__(256) void msl_reduce(
    const double* __restrict__ p, int nblk, float* __restrict__ out)
{
    __shared__ double s_acc[7];
    __shared__ double s_w[4];
    const int tid  = threadIdx.x;
    const int lane = tid & 63;
    const int w    = tid >> 6;

    for (int i = 0; i < 7; ++i) {
        double v = 0.0;
        for (int j = tid; j < nblk; j += 256) v += p[(size_t)i * nblk + j];
#pragma unroll
        for (int off = 32; off > 0; off >>= 1) v += __shfl_xor(v, off);
        if (lane == 0) s_w[w] = v;
        __syncthreads();
        if (tid == 0) s_acc[i] = s_w[0] + s_w[1] + s_w[2] + s_w[3];
        __syncthreads();
    }
    if (tid == 0) {
        const double N  = fmax(s_acc[5], 1.0);
        const double PN = fmax(s_acc[6], 1.0);
        out[0] = (float)(s_acc[0] / N);   // loss_l
        out[1] = (float)(s_acc[1] / N);   // loss_c
        out[2] = (float)(s_acc[2] / PN);  // loss_prop_l
        out[3] = (float)(s_acc[3] / PN);  // loss_prop_c
        out[4] = (float)(s_acc[4] / N);   // loss_ct
    }
}

__global__ void msl_finalize(const double* __restrict__ acc, float* __restrict__ out) {
    const double N  = fmax(acc[5], 1.0);
    const double PN = fmax(acc[6], 1.0);
    out[0] = (float)(acc[0] / N);
    out[1] = (float)(acc[1] / N);
    out[2] = (float)(acc[2] / PN);
    out[3] = (float)(acc[3] / PN);
    out[4] = (float)(acc[4] / N);
}

extern "C" void kernel_launch(void* const* d_in, const int* in_sizes, int n_in,
                              void* d_out, int out_size, void* d_ws, size_t ws_size,
                              hipStream_t stream) {
    const float* loc_data       = (const float*)d_in[0];
    const float* conf_data      = (const float*)d_in[1];
    const float* prop_loc_data  = (const float*)d_in[2];
    const float* prop_conf_data = (const float*)d_in[3];
    const float* center_data    = (const float*)d_in[4];
    const float* priors         = (const float*)d_in[5];
    const float* targets        = (const float*)d_in[6];
    float* out = (float*)d_out;

    const int K = in_sizes[5];            // priors: (K, 1)
    const int B = in_sizes[6] / (NGT * 3);
    const int nblk = (K / 256) * B;

    double* ws = (double*)d_ws;
    dim3 grid(K / 256, B);

    if (ws_size >= (size_t)7 * nblk * sizeof(double)) {
        // contention-free partials + deterministic reduce (no atomics)
        msl_main<true><<<grid, 256, 0, stream>>>(loc_data, conf_data, prop_loc_data,
                                                 prop_conf_data, center_data, priors,
                                                 targets, ws, K, nblk);
        msl_reduce<<<1, 256, 0, stream>>>(ws, nblk, out);
    } else {
        hipMemsetAsync(ws, 0, 7 * sizeof(double), stream);
        msl_main<false><<<grid, 256, 0, stream>>>(loc_data, conf_data, prop_loc_data,
                                                  prop_conf_data, center_data, priors,
                                                  targets, ws, K, nblk);
        msl_finalize<<<1, 1, 0, stream>>>(ws, out);
    }
}

// Round 4
// 72.596 us; speedup vs baseline: 5.0618x; 1.0656x over previous
//
#include <hip/hip_runtime.h>
#include <math.h>

#define NCLS 21
#define NGT 32
#define CLIPLEN 256.0f
#define MAXN 512.0f
#define FEPS 1.1920928955078125e-07f

#define ROWF 21            // floats per class row
#define WCH (64 * ROWF)    // floats per wave chunk (64 anchors) = 1344

// partial layout in d_ws (doubles): p[i * nblk + blk], i in 0..6
// i: 0 loss_l, 1 loss_c, 2 loss_prop_l, 3 loss_prop_c, 4 loss_ct, 5 pos, 6 prop_pos

__device__ __forceinline__ void glds16(const float* g, float* l) {
    __builtin_amdgcn_global_load_lds(
        (const __attribute__((address_space(1))) void*)g,
        (__attribute__((address_space(3))) void*)l, 16, 0, 0);
}
__device__ __forceinline__ void glds4(const float* g, float* l) {
    __builtin_amdgcn_global_load_lds(
        (const __attribute__((address_space(1))) void*)g,
        (__attribute__((address_space(3))) void*)l, 4, 0, 0);
}

// stage one wave's 64 class rows (5376 B) with 5x dwordx4 + 1x dword
__device__ __forceinline__ void stage_rows(const float* g, float* l, int lane) {
#pragma unroll
    for (int i = 0; i < 5; ++i)
        glds16(g + i * 256 + lane * 4, l + i * 256);
    glds4(g + 1280 + lane, l + 1280);
}

__device__ __forceinline__ void load_row(const float* __restrict__ row, float* r) {
#pragma unroll
    for (int i = 0; i < NCLS; ++i) r[i] = row[i];   // ds_read_b128 x5 + b32
}

__device__ __forceinline__ float focal_from_regs(const float* r, int tgt) {
    float m = r[0];
#pragma unroll
    for (int i = 1; i < NCLS; ++i) m = fmaxf(m, r[i]);
    float s = 0.0f;
    float tl = 0.0f;
#pragma unroll
    for (int i = 0; i < NCLS; ++i) {
        s += __expf(r[i] - m);
        if (i == tgt) tl = r[i];      // compile-time index, runtime select
    }
    float lse = m + __logf(s);
    float pt = __expf(tl - lse) + 1e-10f;
    float a = (tgt == 0) ? 0.25f : 0.75f;
    float om = 1.0f - pt;
    return -a * om * om * __logf(pt);
}

template <bool PARTIALS>
__global__ __launch_bounds__(256, 7) void msl_main(
    const float* __restrict__ loc_data,
    const float* __restrict__ conf_data,
    const float* __restrict__ prop_loc_data,
    const float* __restrict__ prop_conf_data,
    const float* __restrict__ center_data,
    const float* __restrict__ priors,
    const float* __restrict__ targets,
    double* __restrict__ ws,
    int K, int nblk)
{
    __shared__ float s_cls[4][WCH];       // ONE matrix buffer per wave, 21504 B
    __shared__ float s_t0[NGT], s_t1[NGT], s_lb[NGT];
    __shared__ float s_red[7 * 4];

    const int b    = blockIdx.y;
    const int tid  = threadIdx.x;
    const int lane = tid & 63;
    const int w    = tid >> 6;
    const int kblk = blockIdx.x * 256;
    const int k    = kblk + tid;
    const size_t idx = (size_t)b * K + k;

    if (tid < NGT) {
        const float* tg = targets + ((size_t)b * NGT + tid) * 3;
        s_t0[tid] = tg[0];
        s_t1[tid] = tg[1];
        s_lb[tid] = tg[2];
    }

    const size_t chunk0 = ((size_t)b * K + kblk + w * 64) * ROWF;
    float* lbuf = &s_cls[w][0];

    // ---- stage conf rows (6 VMEM in flight) ----
    stage_rows(conf_data + chunk0, lbuf, lane);

    // ---- per-anchor small loads (coalesced, overlap staging) ----
    const float2 loc = ((const float2*)loc_data)[idx];
    const float2 plo = ((const float2*)prop_loc_data)[idx];
    const float  x   = center_data[idx];
    const float  c   = priors[k];

    __syncthreads();   // targets visible

    // ---- match: argmin over 32 GTs (first occurrence of min) ----
    float bestA = 3.0e38f;
    int bestN = 0;
#pragma unroll
    for (int n = 0; n < NGT; ++n) {
        float l = (c - s_t0[n]) * CLIPLEN;
        float r = (s_t1[n] - c) * CLIPLEN;
        float a = (l < 0.0f || r < 0.0f) ? MAXN : (l + r);
        if (a < bestA) { bestA = a; bestN = n; }
    }
    const float t0 = s_t0[bestN];
    const float t1 = s_t1[bestN];
    const float tl = (c - t0) * CLIPLEN;
    const float tr = (t1 - c) * CLIPLEN;
    int conf_t = (bestA >= MAXN) ? 0 : (int)s_lb[bestN];

    const float pl = loc.x, pr = loc.y;

    // ---- IoU(loc_data, loc_t) ----
    const float inter = fminf(pl, tl) + fminf(pr, tr);
    const float uni   = pl + pr + tl + tr - inter;
    const float iou   = inter / fmaxf(uni, FEPS);

    const int prop_conf_t = (iou < 0.5f) ? 0 : conf_t;
    const float posf = (conf_t > 0) ? 1.0f : 0.0f;
    const float ppf  = (prop_conf_t > 0) ? 1.0f : 0.0f;

    // ---- loss_l: GIoU ----
    const float ac   = fmaxf(pl, tl) + fmaxf(pr, tr);
    const float giou = iou - (ac - uni) / fmaxf(ac, FEPS);
    const float v_ll = (1.0f - giou) * posf;

    // ---- loss_prop_l ----
    const float prop_w = pl + pr;
    const float inv_hw = 1.0f / (0.5f * prop_w);
    const float plt0 = (tl - pl) * inv_hw;
    const float plt1 = (tr - pr) * inv_hw;
    const float v_lpl = (fabsf(plo.x - plt0) + fabsf(plo.y - plt1)) * ppf;

    // ---- loss_ct ----
    const float cur0 = 0.5f * prop_w * plo.x + pl;
    const float cur1 = 0.5f * prop_w * plo.y + pr;
    const float in2  = fminf(cur0, tl) + fminf(cur1, tr);
    const float un2  = cur0 + cur1 + tl + tr - in2;
    const float iou2 = fmaxf(in2 / fmaxf(un2, FEPS), 0.0f);
    const float bce  = fmaxf(x, 0.0f) - x * iou2 + log1pf(__expf(-fabsf(x)));
    const float v_ct = bce * posf;

    // ---- focal conf: wait staging, pull row to regs, then reuse buffer ----
    asm volatile("s_waitcnt vmcnt(0)" ::: "memory");
    __builtin_amdgcn_sched_barrier(0);
    const float* rowp = lbuf + lane * ROWF;
    float rr[NCLS];
    load_row(rowp, rr);
    asm volatile("s_waitcnt lgkmcnt(0)" ::: "memory");   // row fully in regs
    __builtin_amdgcn_sched_barrier(0);

    // stage prop_conf into the SAME per-wave buffer (no cross-wave hazard)
    stage_rows(prop_conf_data + chunk0, lbuf, lane);

    const float v_lc = focal_from_regs(rr, conf_t);      // overlaps staging

    asm volatile("s_waitcnt vmcnt(0)" ::: "memory");
    __builtin_amdgcn_sched_barrier(0);
    load_row(rowp, rr);
    const float v_lpc = focal_from_regs(rr, prop_conf_t);

    // ---- block reduction ----
    float vals[7] = { v_ll, v_lc, v_lpl, v_lpc, v_ct, posf, ppf };
#pragma unroll
    for (int i = 0; i < 7; ++i) {
        float v = vals[i];
#pragma unroll
        for (int off = 32; off > 0; off >>= 1) v += __shfl_xor(v, off);
        if (lane == 0) s_red[i * 4 + w] = v;
    }
    __syncthreads();
    if (tid == 0) {
        const int blk = blockIdx.y * gridDim.x + blockIdx.x;
#pragma unroll
        for (int i = 0; i < 7; ++i) {
            double s = (double)s_red[i * 4 + 0] + (double)s_red[i * 4 + 1]
                     + (double)s_red[i * 4 + 2] + (double)s_red[i * 4 + 3];
            if (PARTIALS) ws[(size_t)i * nblk + blk] = s;   // contention-free store
            else          atomicAdd(&ws[i], s);
        }
    }
}

// Single-block deterministic reduction of per-block partials -> 5 outputs.
__global__ __launch_bounds__(256) void msl_reduce(
    const double* __restrict__ p, int nblk, float* __restrict__ out)
{
    __shared__ double s_acc[7];
    __shared__ double s_w[4];
    const int tid  = threadIdx.x;
    const int lane = tid & 63;
    const int w    = tid >> 6;

    for (int i = 0; i < 7; ++i) {
        double v = 0.0;
        for (int j = tid; j < nblk; j += 256) v += p[(size_t)i * nblk + j];
#pragma unroll
        for (int off = 32; off > 0; off >>= 1) v += __shfl_xor(v, off);
        if (lane == 0) s_w[w] = v;
        __syncthreads();
        if (tid == 0) s_acc[i] = s_w[0] + s_w[1] + s_w[2] + s_w[3];
        __syncthreads();
    }
    if (tid == 0) {
        const double N  = fmax(s_acc[5], 1.0);
        const double PN = fmax(s_acc[6], 1.0);
        out[0] = (float)(s_acc[0] / N);   // loss_l
        out[1] = (float)(s_acc[1] / N);   // loss_c
        out[2] = (float)(s_acc[2] / PN);  // loss_prop_l
        out[3] = (float)(s_acc[3] / PN);  // loss_prop_c
        out[4] = (float)(s_acc[4] / N);   // loss_ct
    }
}

__global__ void msl_finalize(const double* __restrict__ acc, float* __restrict__ out) {
    const double N  = fmax(acc[5], 1.0);
    const double PN = fmax(acc[6], 1.0);
    out[0] = (float)(acc[0] / N);
    out[1] = (float)(acc[1] / N);
    out[2] = (float)(acc[2] / PN);
    out[3] = (float)(acc[3] / PN);
    out[4] = (float)(acc[4] / N);
}

extern "C" void kernel_launch(void* const* d_in, const int* in_sizes, int n_in,
                              void* d_out, int out_size, void* d_ws, size_t ws_size,
                              hipStream_t stream) {
    const float* loc_data       = (const float*)d_in[0];
    const float* conf_data      = (const float*)d_in[1];
    const float* prop_loc_data  = (const float*)d_in[2];
    const float* prop_conf_data = (const float*)d_in[3];
    const float* center_data    = (const float*)d_in[4];
    const float* priors         = (const float*)d_in[5];
    const float* targets        = (const float*)d_in[6];
    float* out = (float*)d_out;

    const int K = in_sizes[5];            // priors: (K, 1)
    const int B = in_sizes[6] / (NGT * 3);
    const int nblk = (K / 256) * B;

    double* ws = (double*)d_ws;
    dim3 grid(K / 256, B);

    if (ws_size >= (size_t)7 * nblk * sizeof(double)) {
        // contention-free partials + deterministic reduce (no atomics)
        msl_main<true><<<grid, 256, 0, stream>>>(loc_data, conf_data, prop_loc_data,
                                                 prop_conf_data, center_data, priors,
                                                 targets, ws, K, nblk);
        msl_reduce<<<1, 256, 0, stream>>>(ws, nblk, out);
    } else {
        hipMemsetAsync(ws, 0, 7 * sizeof(double), stream);
        msl_main<false><<<grid, 256, 0, stream>>>(loc_data, conf_data, prop_loc_data,
                                                  prop_conf_data, center_data, priors,
                                                  targets, ws, K, nblk);
        msl_finalize<<<1, 1, 0, stream>>>(ws, out);
    }
}

// Round 5
// 68.350 us; speedup vs baseline: 5.3763x; 1.0621x over previous
//
#include <hip/hip_runtime.h>
#include <math.h>

#define NCLS 21
#define NGT 32
#define CLIPLEN 256.0f
#define MAXN 512.0f
#define FEPS 1.1920928955078125e-07f

#define ROWF 21            // floats per class row
#define WCH (64 * ROWF)    // floats per wave chunk (64 anchors) = 1344

// partial layout in d_ws (doubles): p[i * nblk + blk], i in 0..6
// i: 0 loss_l, 1 loss_c, 2 loss_prop_l, 3 loss_prop_c, 4 loss_ct, 5 pos, 6 prop_pos

__device__ __forceinline__ float fastrcp(float x) { return __builtin_amdgcn_rcpf(x); }

__device__ __forceinline__ void glds16(const float* g, float* l) {
    __builtin_amdgcn_global_load_lds(
        (const __attribute__((address_space(1))) void*)g,
        (__attribute__((address_space(3))) void*)l, 16, 0, 0);
}
__device__ __forceinline__ void glds4(const float* g, float* l) {
    __builtin_amdgcn_global_load_lds(
        (const __attribute__((address_space(1))) void*)g,
        (__attribute__((address_space(3))) void*)l, 4, 0, 0);
}

// stage one wave's 64 class rows (5376 B) with 5x dwordx4 + 1x dword
__device__ __forceinline__ void stage_rows(const float* g, float* l, int lane) {
#pragma unroll
    for (int i = 0; i < 5; ++i)
        glds16(g + i * 256 + lane * 4, l + i * 256);
    glds4(g + 1280 + lane, l + 1280);
}

__device__ __forceinline__ void load_row(const float* __restrict__ row, float* r) {
#pragma unroll
    for (int i = 0; i < NCLS; ++i) r[i] = row[i];   // ds_read_b128 x5 + b32
}

// focal with shared exp: rt = r[tgt] (fetched separately via ds_read)
__device__ __forceinline__ float focal_from(const float* r, float rt, int tgt) {
    // max via v_max3 tree
    float m0 = fmaxf(fmaxf(r[0],  r[1]),  r[2]);
    float m1 = fmaxf(fmaxf(r[3],  r[4]),  r[5]);
    float m2 = fmaxf(fmaxf(r[6],  r[7]),  r[8]);
    float m3 = fmaxf(fmaxf(r[9],  r[10]), r[11]);
    float m4 = fmaxf(fmaxf(r[12], r[13]), r[14]);
    float m5 = fmaxf(fmaxf(r[15], r[16]), r[17]);
    float m6 = fmaxf(fmaxf(r[18], r[19]), r[20]);
    float ma = fmaxf(fmaxf(m0, m1), m2);
    float mb = fmaxf(fmaxf(m3, m4), m5);
    float m  = fmaxf(fmaxf(ma, mb), m6);

    float e[NCLS];
#pragma unroll
    for (int i = 0; i < NCLS; ++i) e[i] = __expf(r[i] - m);
    // pairwise sum tree (short dependency chains)
    float s0 = (e[0] + e[1])  + (e[2] + e[3]);
    float s1 = (e[4] + e[5])  + (e[6] + e[7]);
    float s2 = (e[8] + e[9])  + (e[10] + e[11]);
    float s3 = (e[12] + e[13]) + (e[14] + e[15]);
    float s4 = (e[16] + e[17]) + (e[18] + e[19]);
    float s  = ((s0 + s1) + (s2 + s3)) + (s4 + e[20]);

    float pt  = __expf(rt - m) * fastrcp(s) + 1e-10f;
    float lpt = __logf(pt);
    float a   = (tgt == 0) ? 0.25f : 0.75f;
    float om  = 1.0f - pt;
    return -a * om * om * lpt;
}

template <bool PARTIALS>
__global__ __launch_bounds__(256, 7) void msl_main(
    const float* __restrict__ loc_data,
    const float* __restrict__ conf_data,
    const float* __restrict__ prop_loc_data,
    const float* __restrict__ prop_conf_data,
    const float* __restrict__ center_data,
    const float* __restrict__ priors,
    const float* __restrict__ targets,
    double* __restrict__ ws,
    int K, int nblk)
{
    __shared__ float s_cls[4][WCH];       // ONE matrix buffer per wave, 21504 B
    __shared__ float s_t0[NGT], s_t1[NGT], s_lb[NGT];
    __shared__ float s_red[6 * 4];

    const int b    = blockIdx.y;
    const int tid  = threadIdx.x;
    const int lane = tid & 63;
    const int w    = tid >> 6;
    const int kblk = blockIdx.x * 256;
    const int k    = kblk + tid;
    const size_t idx = (size_t)b * K + k;

    if (tid < NGT) {
        const float* tg = targets + ((size_t)b * NGT + tid) * 3;
        s_t0[tid] = tg[0];
        s_t1[tid] = tg[1];
        s_lb[tid] = tg[2];
    }

    const size_t chunk0 = ((size_t)b * K + kblk + w * 64) * ROWF;
    float* lbuf = &s_cls[w][0];

    // ---- stage conf rows (6 VMEM in flight) ----
    stage_rows(conf_data + chunk0, lbuf, lane);

    // ---- per-anchor small loads (coalesced, overlap staging) ----
    const float2 loc = ((const float2*)loc_data)[idx];
    const float2 plo = ((const float2*)prop_loc_data)[idx];
    const float  x   = center_data[idx];
    const float  c   = priors[k];

    __syncthreads();   // targets visible

    // ---- match: argmin over 32 GTs via scalar (SGPR) targets ----
    // area = inside ? (t1-t0)*256 : 512  (inside length always < 52 < 512)
    const float* tgs = targets + (size_t)b * (NGT * 3);   // uniform -> s_load
    float bestA = 3.0e38f;
    int bestN = 0;
#pragma unroll
    for (int n = 0; n < NGT; ++n) {
        const float t0n = tgs[3 * n];
        const float t1n = tgs[3 * n + 1];
        const bool outside = (t0n > c) || (t1n < c);
        const float cand = outside ? MAXN : (t1n - t0n) * CLIPLEN;
        const bool better = cand < bestA;
        bestA = better ? cand : bestA;
        bestN = better ? n : bestN;
    }
    const float t0 = s_t0[bestN];
    const float t1 = s_t1[bestN];
    const float tl = (c - t0) * CLIPLEN;
    const float tr = (t1 - c) * CLIPLEN;
    int conf_t = (bestA >= MAXN) ? 0 : (int)s_lb[bestN];

    const float pl = loc.x, pr = loc.y;

    // ---- IoU(loc_data, loc_t) ----
    const float inter = fminf(pl, tl) + fminf(pr, tr);
    const float uni   = pl + pr + tl + tr - inter;
    const float iou   = inter * fastrcp(fmaxf(uni, FEPS));

    const int prop_conf_t = (iou < 0.5f) ? 0 : conf_t;
    const float posf = (conf_t > 0) ? 1.0f : 0.0f;
    const float ppf  = (prop_conf_t > 0) ? 1.0f : 0.0f;

    // ---- loss_l: GIoU ----
    const float ac   = fmaxf(pl, tl) + fmaxf(pr, tr);
    const float giou = iou - (ac - uni) * fastrcp(fmaxf(ac, FEPS));
    const float v_ll = (1.0f - giou) * posf;

    // ---- loss_prop_l ----
    const float prop_w = pl + pr;
    const float inv_hw = 2.0f * fastrcp(prop_w);
    const float plt0 = (tl - pl) * inv_hw;
    const float plt1 = (tr - pr) * inv_hw;
    const float v_lpl = (fabsf(plo.x - plt0) + fabsf(plo.y - plt1)) * ppf;

    // ---- loss_ct ----
    const float cur0 = 0.5f * prop_w * plo.x + pl;
    const float cur1 = 0.5f * prop_w * plo.y + pr;
    const float in2  = fminf(cur0, tl) + fminf(cur1, tr);
    const float un2  = cur0 + cur1 + tl + tr - in2;
    const float iou2 = fmaxf(in2 * fastrcp(fmaxf(un2, FEPS)), 0.0f);
    const float ebx  = __expf(-fabsf(x));
    const float bce  = fmaxf(x, 0.0f) - x * iou2 + __logf(1.0f + ebx);
    const float v_ct = bce * posf;

    // ---- focal conf: wait staging, pull row + r[tgt] to regs, reuse buffer ----
    asm volatile("s_waitcnt vmcnt(0)" ::: "memory");
    __builtin_amdgcn_sched_barrier(0);
    const float* rowp = lbuf + lane * ROWF;
    float rr[NCLS];
    load_row(rowp, rr);
    const float rt_c = rowp[conf_t];                     // 1 divergent ds_read
    asm volatile("s_waitcnt lgkmcnt(0)" ::: "memory");   // rows fully in regs
    __builtin_amdgcn_sched_barrier(0);

    // stage prop_conf into the SAME per-wave buffer (no cross-wave hazard)
    stage_rows(prop_conf_data + chunk0, lbuf, lane);

    const float v_lc = focal_from(rr, rt_c, conf_t);     // overlaps staging

    asm volatile("s_waitcnt vmcnt(0)" ::: "memory");
    __builtin_amdgcn_sched_barrier(0);
    load_row(rowp, rr);
    const float rt_p = rowp[prop_conf_t];
    const float v_lpc = focal_from(rr, rt_p, prop_conf_t);

    // ---- block reduction (counts packed: posf + 4096*ppf, both <= 64/wave) ----
    float vals[6] = { v_ll, v_lc, v_lpl, v_lpc, v_ct, posf + 4096.0f * ppf };
#pragma unroll
    for (int i = 0; i < 6; ++i) {
        float v = vals[i];
#pragma unroll
        for (int off = 32; off > 0; off >>= 1) v += __shfl_xor(v, off);
        if (lane == 0) s_red[i * 4 + w] = v;
    }
    __syncthreads();
    if (tid == 0) {
        const int blk = blockIdx.y * gridDim.x + blockIdx.x;
#pragma unroll
        for (int i = 0; i < 5; ++i) {
            double s = (double)s_red[i * 4 + 0] + (double)s_red[i * 4 + 1]
                     + (double)s_red[i * 4 + 2] + (double)s_red[i * 4 + 3];
            if (PARTIALS) ws[(size_t)i * nblk + blk] = s;
            else          atomicAdd(&ws[i], s);
        }
        double ct = (double)s_red[5 * 4 + 0] + (double)s_red[5 * 4 + 1]
                  + (double)s_red[5 * 4 + 2] + (double)s_red[5 * 4 + 3];
        double pp = floor(ct / 4096.0);       // prop_pos count (exact)
        double ps = ct - 4096.0 * pp;         // pos count (exact)
        if (PARTIALS) {
            ws[(size_t)5 * nblk + blk] = ps;
            ws[(size_t)6 * nblk + blk] = pp;
        } else {
            atomicAdd(&ws[5], ps);
            atomicAdd(&ws[6], pp);
        }
    }
}

// Single-block deterministic reduction of per-block partials -> 5 outputs.
__global__ __launch_bounds__(256) void msl_reduce(
    const double* __restrict__ p, int nblk, float* __restrict__ out)
{
    __shared__ double s_acc[7];
    __shared__ double s_w[4];
    const int tid  = threadIdx.x;
    const int lane = tid & 63;
    const int w    = tid >> 6;

    for (int i = 0; i < 7; ++i) {
        double v = 0.0;
        for (int j = tid; j < nblk; j += 256) v += p[(size_t)i * nblk + j];
#pragma unroll
        for (int off = 32; off > 0; off >>= 1) v += __shfl_xor(v, off);
        if (lane == 0) s_w[w] = v;
        __syncthreads();
        if (tid == 0) s_acc[i] = s_w[0] + s_w[1] + s_w[2] + s_w[3];
        __syncthreads();
    }
    if (tid == 0) {
        const double N  = fmax(s_acc[5], 1.0);
        const double PN = fmax(s_acc[6], 1.0);
        out[0] = (float)(s_acc[0] / N);   // loss_l
        out[1] = (float)(s_acc[1] / N);   // loss_c
        out[2] = (float)(s_acc[2] / PN);  // loss_prop_l
        out[3] = (float)(s_acc[3] / PN);  // loss_prop_c
        out[4] = (float)(s_acc[4] / N);   // loss_ct
    }
}

__global__ void msl_finalize(const double* __restrict__ acc, float* __restrict__ out) {
    const double N  = fmax(acc[5], 1.0);
    const double PN = fmax(acc[6], 1.0);
    out[0] = (float)(acc[0] / N);
    out[1] = (float)(acc[1] / N);
    out[2] = (float)(acc[2] / PN);
    out[3] = (float)(acc[3] / PN);
    out[4] = (float)(acc[4] / N);
}

extern "C" void kernel_launch(void* const* d_in, const int* in_sizes, int n_in,
                              void* d_out, int out_size, void* d_ws, size_t ws_size,
                              hipStream_t stream) {
    const float* loc_data       = (const float*)d_in[0];
    const float* conf_data      = (const float*)d_in[1];
    const float* prop_loc_data  = (const float*)d_in[2];
    const float* prop_conf_data = (const float*)d_in[3];
    const float* center_data    = (const float*)d_in[4];
    const float* priors         = (const float*)d_in[5];
    const float* targets        = (const float*)d_in[6];
    float* out = (float*)d_out;

    const int K = in_sizes[5];            // priors: (K, 1)
    const int B = in_sizes[6] / (NGT * 3);
    const int nblk = (K / 256) * B;

    double* ws = (double*)d_ws;
    dim3 grid(K / 256, B);

    if (ws_size >= (size_t)7 * nblk * sizeof(double)) {
        // contention-free partials + deterministic reduce (no atomics)
        msl_main<true><<<grid, 256, 0, stream>>>(loc_data, conf_data, prop_loc_data,
                                                 prop_conf_data, center_data, priors,
                                                 targets, ws, K, nblk);
        msl_reduce<<<1, 256, 0, stream>>>(ws, nblk, out);
    } else {
        hipMemsetAsync(ws, 0, 7 * sizeof(double), stream);
        msl_main<false><<<grid, 256, 0, stream>>>(loc_data, conf_data, prop_loc_data,
                                                  prop_conf_data, center_data, priors,
                                                  targets, ws, K, nblk);
        msl_finalize<<<1, 1, 0, stream>>>(ws, out);
    }
}